// Round 22
// baseline (1171.313 us; speedup 1.0000x reference)
//
#include <hip/hip_runtime.h>

#define ATOM  14
#define BOND  3
#define INNER 20
#define HID   34
#define HIDP  36             // HID padded for LDS rows
#define REC   20
#define OHID  25
#define NN    1048576
#define NE    983040
#define NG    16384

#define NB    1024           // prep persistent grid (4 blocks/CU @ VGPR16: co-resident)
#define NT    256
#define GT    (NB*NT)        // 262144
#define NIT   (NN/GT)        // 4 strided iterations in node phases

#define NB2   1024           // level blocks (independent tree-bins)
#define NT2   256            // 4 waves
#define NGRP  (NT2/4)        // 64 node-groups (4 lanes each) per block
#define SSTR  (NGRP+1)       // 65: stride-padded staging
#define NBINS (NB2*32)       // bin = blk*32 + depth*2 + isLeaf

__device__ __forceinline__ float leaky(float x) { return x >= 0.f ? x : 0.01f * x; }

__device__ __forceinline__ void wsync() {
    __builtin_amdgcn_wave_barrier();
    __builtin_amdgcn_sched_barrier(0);
}

// grid-wide barrier for prep only: device-scope fences (cross-XCD safe)
__device__ __forceinline__ void gbar_f(int* bar, int goal) {
    __syncthreads();
    if (threadIdx.x == 0) {
        __threadfence();
        __hip_atomic_fetch_add(bar, 1, __ATOMIC_RELEASE, __HIP_MEMORY_SCOPE_AGENT);
        while (__hip_atomic_load(bar, __ATOMIC_RELAXED, __HIP_MEMORY_SCOPE_AGENT) < goal)
            __builtin_amdgcn_s_sleep(32);
        __threadfence();
    }
    __syncthreads();
}

__global__ void k_pre(int* cnt_n, int2* pnode2, float* g, int* bin_cnt, int* totals, int* bars) {
    int tid = blockIdx.x * 256 + threadIdx.x;          // 262144 threads
    for (int i = tid; i < NN; i += 262144) { cnt_n[i] = 0; pnode2[i] = make_int2(i, -1); }
    for (int i = tid; i < NG * REC; i += 262144) g[i] = 0.f;
    for (int i = tid; i < NBINS; i += 262144) bin_cnt[i] = 0;
    if (tid == 0) { totals[0] = 0; totals[16] = 0; }
    if (tid == 1) for (int k = 0; k < 32; ++k) bars[k] = 0;
}

// ---------------- prep: counts+rank, root-chase, sort+row-alloc, child pass ----------------
__global__ __launch_bounds__(NT) void k_prep(
    const int* __restrict__ parent, const int* __restrict__ child,
    const int* __restrict__ depth, const int* __restrict__ gid,
    const float* __restrict__ isr,
    int* cnt_n, int2* pnode2, int* K_s,
    int4* nodeinfo, int* row_n, int* adjc,
    int* bin_cnt, int* bin_base, int* bin_cur,
    int* totals, int* bar)
{
    __shared__ int sh[NT];
    __shared__ int sbase_sh;
    const int t = threadIdx.x;
    const int tid = blockIdx.x * NT + t;
    int ep = 0;

    // P0: child counts (returns rank) + packed (parent, rank|eid) per child
    for (int e = tid; e < NE; e += GT) {
        int p = parent[e];
        int r = atomicAdd(&cnt_n[p], 1);
        pnode2[child[e]] = make_int2(p, (r << 20) | e);
    }
    gbar_f(bar, NB * ++ep);

    // P1: per-node root chase + bin key + histogram
    for (int i = tid; i < NN; i += GT) {
        int d = depth[i];
        int r = i;
        for (int s = 0; s < d; ++s) r = pnode2[r].x;   // fixed-point safe at roots
        int K = (r & (NB2 - 1)) * 32 + d * 2 + (cnt_n[i] == 0 ? 1 : 0);
        K_s[i] = K;
        atomicAdd(&bin_cnt[K], 1);
    }
    gbar_f(bar, NB * ++ep);

    // P2: bin scan (orderless base): blocks 0..127, 256 bins each
    if (blockIdx.x < NBINS / NT) {
        int k0 = blockIdx.x * NT + t;
        int v = bin_cnt[k0];
        sh[t] = v;
        __syncthreads();
        for (int ofs = 1; ofs < NT; ofs <<= 1) {
            int x = (t >= ofs) ? sh[t - ofs] : 0;
            __syncthreads();
            sh[t] += x;
            __syncthreads();
        }
        if (t == NT - 1) sbase_sh = atomicAdd(&totals[0], sh[t]);
        __syncthreads();
        int b = sbase_sh + sh[t] - v;
        bin_base[k0] = b;
        bin_cur[k0] = b;
    }
    gbar_f(bar, NB * ++ep);

    // P3: counting-sort scatter + fused orderless row allocation.
    // One packed 16B scattered write per node; row_n coalesced.
    for (int k = 0; k < NIT; ++k) {
        int i = tid + k * GT;
        int cn = cnt_n[i];
        __syncthreads();                     // protect sh reuse
        sh[t] = cn;
        __syncthreads();
        for (int ofs = 1; ofs < NT; ofs <<= 1) {
            int x = (t >= ofs) ? sh[t - ofs] : 0;
            __syncthreads();
            sh[t] += x;
            __syncthreads();
        }
        if (t == NT - 1) sbase_sh = atomicAdd(&totals[16], sh[t]);
        __syncthreads();
        int row = sbase_sh + sh[t] - cn;     // exclusive prefix + block base
        int pos = atomicAdd(&bin_cur[K_s[i]], 1);
        int2 pe = pnode2[i];                 // coalesced
        int gr = (isr[i] != 0.f) ? gid[i] : -1;   // coalesced
        nodeinfo[pos] = make_int4(i, pe.y, gr, (row << 12) | cn);  // scattered 16B
        row_n[i] = row;                      // coalesced
    }
    gbar_f(bar, NB * ++ep);

    // P4: child pass in pos order — no atomics; only adjc is a scattered write
    for (int pos = tid; pos < NN; pos += GT) {
        int4 ni = nodeinfo[pos];             // coalesced
        if (ni.z < 0) {                      // non-root => has a parent edge
            int ppn = pnode2[ni.x].x;        // scattered read (hot 8MB)
            int rank = ((unsigned)ni.y) >> 20;
            int slot = row_n[ppn] + rank;    // scattered read (4MB)
            adjc[slot] = pos;                // scattered 4B write
        }
    }
}

// cooperative MLP phases 1-2 (x pre-staged in xs column `slot`): lane j owns
// hidden units 9j..9j+8 and outputs 5j..5j+4. Result: o[5] + os column.
__device__ __forceinline__ void coop_mlp(int slot, int j, int KN,
                                         const float* xs, float* hs, float* os,
                                         const float* w1, const float* b1,
                                         const float* w2, const float* b2,
                                         float* o)
{
    wsync();                       // xs writes (all lanes) before xs reads
    float acc[9];
    #pragma unroll
    for (int u = 0; u < 9; ++u) { int h = 9*j + u; acc[u] = (h < HID) ? b1[h] : 0.f; }
    #pragma unroll 2
    for (int k = 0; k < KN; ++k) {
        float xk = xs[k * SSTR + slot];
        #pragma unroll
        for (int u = 0; u < 9; ++u) { int h = 9*j + u; if (h < HID) acc[u] += xk * w1[k * HIDP + h]; }
    }
    #pragma unroll
    for (int u = 0; u < 9; ++u) { int h = 9*j + u; if (h < HID) hs[h * SSTR + slot] = leaky(acc[u]); }
    wsync();                       // hs writes before hs reads
    #pragma unroll
    for (int u = 0; u < 5; ++u) o[u] = b2[5*j + u];
    #pragma unroll 2
    for (int k = 0; k < HID; ++k) {
        float hk = hs[k * SSTR + slot];
        #pragma unroll
        for (int u = 0; u < 5; ++u) o[u] += hk * w2[k * REC + 5*j + u];
    }
    #pragma unroll
    for (int u = 0; u < 5; ++u) { o[u] = leaky(o[u]); os[(5*j + u) * SSTR + slot] = o[u]; }
    wsync();                       // os writes before os reads (msg phase)
}

// ---------------- levels: 4 lanes per node, packed nodeinfo, bond by eid ----------------
__global__ __launch_bounds__(NT2) void k_levels(
    const float* __restrict__ atom, const float* __restrict__ bond,
    const int4* __restrict__ nodeinfo, const int* __restrict__ adjc,
    const int* __restrict__ bin_base, const int* __restrict__ bin_cnt,
    const float* __restrict__ iw, const float* __restrict__ ib,
    const float* __restrict__ nw1, const float* __restrict__ nb1,
    const float* __restrict__ nw2, const float* __restrict__ nb2,
    const float* __restrict__ l0w1, const float* __restrict__ l0b1,
    const float* __restrict__ l0w2, const float* __restrict__ l0b2,
    float* __restrict__ g, float* __restrict__ msg_s)
{
    __shared__ float lw1[34 * HIDP];     // net_w1  [34][36]
    __shared__ float lw2[HID * REC];     // net_w2  [34][20]
    __shared__ float liw[23 * REC];      // inner_w [23][20]
    __shared__ float zw1[ATOM * HIDP];   // net0_w1 [14][36]
    __shared__ float zw2[HID * REC];     // net0_w2 [34][20]
    __shared__ float lb1[HID], lb2[REC], lbi[INNER], zb1[HID], zb2[REC];
    __shared__ float xs[34 * SSTR];      // x staging   [34][65]
    __shared__ float hs[34 * SSTR];      // hid staging [34][65]
    __shared__ float os[20 * SSTR];      // out staging [20][65]

    const int t = threadIdx.x;
    const int b = blockIdx.x;
    const int slot = t >> 2;             // node-group 0..63
    const int j = t & 3;                 // lane slice 0..3

    for (int idx = t; idx < 34 * HIDP; idx += NT2) {
        int r = idx / HIDP, c = idx - r * HIDP;
        lw1[idx] = (c < HID) ? nw1[r * HID + c] : 0.f;
    }
    for (int idx = t; idx < HID * REC; idx += NT2) { lw2[idx] = nw2[idx]; zw2[idx] = l0w2[idx]; }
    for (int idx = t; idx < 23 * REC; idx += NT2) liw[idx] = iw[idx];
    for (int idx = t; idx < ATOM * HIDP; idx += NT2) {
        int r = idx / HIDP, c = idx - r * HIDP;
        zw1[idx] = (c < HID) ? l0w1[r * HID + c] : 0.f;
    }
    if (t < HID) { lb1[t] = nb1[t]; zb1[t] = l0b1[t]; }
    else if (t >= 64 && t < 64 + REC) { lb2[t - 64] = nb2[t - 64]; zb2[t - 64] = l0b2[t - 64]; }
    if (t >= 96 && t < 96 + INNER) lbi[t - 96] = ib[t - 96];
    __syncthreads();

    for (int d = 15; d >= 0; --d) {
        // ---- internal nodes (bin b*32 + d*2) ----
        {
            int K = b * 32 + d * 2;
            int base = bin_base[K], n0 = bin_cnt[K];
            for (int idx = slot; idx < n0; idx += NGRP) {
                int pos = base + idx;
                int4 ni = nodeinfo[pos];                // {i, rank|eid, gr, row|n}
                int n   = ni.w & 0xFFF;
                int rp0 = ((unsigned)ni.w) >> 12;
                // gather: lane j sums msg slice q in [5j,5j+5)
                float s0 = 0.f, s1 = 0.f, s2 = 0.f, s3 = 0.f, s4 = 0.f;
                for (int r = rp0; r < rp0 + n; ++r) {
                    const float* mp = msg_s + (size_t)adjc[r] * REC + 5*j;
                    s0 += mp[0]; s1 += mp[1]; s2 += mp[2]; s3 += mp[3]; s4 += mp[4];
                }
                // stage x = [atom, isum]
                const float* ar = atom + (size_t)ni.x * ATOM;
                #pragma unroll
                for (int u = 0; u < 4; ++u) { int k = 4*j + u; if (k < ATOM) xs[k * SSTR + slot] = ar[k]; }
                xs[(ATOM + 5*j + 0) * SSTR + slot] = s0;
                xs[(ATOM + 5*j + 1) * SSTR + slot] = s1;
                xs[(ATOM + 5*j + 2) * SSTR + slot] = s2;
                xs[(ATOM + 5*j + 3) * SSTR + slot] = s3;
                xs[(ATOM + 5*j + 4) * SSTR + slot] = s4;
                float o[5];
                coop_mlp(slot, j, ATOM + INNER, xs, hs, os, lw1, lb1, lw2, lb2, o);
                if (ni.z >= 0) {
                    #pragma unroll
                    for (int u = 0; u < 5; ++u) atomicAdd(&g[(size_t)ni.z * REC + 5*j + u], o[u]);
                } else {
                    const float* br = bond + (size_t)(ni.y & 0xFFFFF) * BOND;
                    float b0 = br[0], b1 = br[1], b2 = br[2];
                    float m[5];
                    #pragma unroll
                    for (int u = 0; u < 5; ++u)
                        m[u] = lbi[5*j + u] + b0 * liw[0 * INNER + 5*j + u]
                             + b1 * liw[1 * INNER + 5*j + u] + b2 * liw[2 * INNER + 5*j + u];
                    #pragma unroll 2
                    for (int k = 0; k < REC; ++k) {
                        float ok = os[k * SSTR + slot];
                        #pragma unroll
                        for (int u = 0; u < 5; ++u) m[u] += ok * liw[(BOND + k) * INNER + 5*j + u];
                    }
                    #pragma unroll
                    for (int u = 0; u < 5; ++u) msg_s[(size_t)pos * REC + 5*j + u] = leaky(m[u]);
                }
            }
        }
        // ---- leaves (bin b*32 + d*2 + 1) ----
        {
            int K = b * 32 + d * 2 + 1;
            int base = bin_base[K], n1 = bin_cnt[K];
            for (int idx = slot; idx < n1; idx += NGRP) {
                int pos = base + idx;
                int4 ni = nodeinfo[pos];
                const float* ar = atom + (size_t)ni.x * ATOM;
                #pragma unroll
                for (int u = 0; u < 4; ++u) { int k = 4*j + u; if (k < ATOM) xs[k * SSTR + slot] = ar[k]; }
                float o[5];
                coop_mlp(slot, j, ATOM, xs, hs, os, zw1, zb1, zw2, zb2, o);
                if (ni.z >= 0) {
                    #pragma unroll
                    for (int u = 0; u < 5; ++u) atomicAdd(&g[(size_t)ni.z * REC + 5*j + u], o[u]);
                } else {
                    const float* br = bond + (size_t)(ni.y & 0xFFFFF) * BOND;
                    float b0 = br[0], b1 = br[1], b2 = br[2];
                    float m[5];
                    #pragma unroll
                    for (int u = 0; u < 5; ++u)
                        m[u] = lbi[5*j + u] + b0 * liw[0 * INNER + 5*j + u]
                             + b1 * liw[1 * INNER + 5*j + u] + b2 * liw[2 * INNER + 5*j + u];
                    #pragma unroll 2
                    for (int k = 0; k < REC; ++k) {
                        float ok = os[k * SSTR + slot];
                        #pragma unroll
                        for (int u = 0; u < 5; ++u) m[u] += ok * liw[(BOND + k) * INNER + 5*j + u];
                    }
                    #pragma unroll
                    for (int u = 0; u < 5; ++u) msg_s[(size_t)pos * REC + 5*j + u] = leaky(m[u]);
                }
            }
        }
        // block-local level barrier (msg producer->consumer across waves)
        __threadfence_block();
        __syncthreads();
    }
}

// ---------------- readout ----------------
__global__ void k_out(const float* __restrict__ g,
                      const float* __restrict__ w1, const float* __restrict__ b1,
                      const float* __restrict__ w2, const float* __restrict__ b2,
                      float* __restrict__ out) {
    int t = blockIdx.x * 256 + threadIdx.x;
    if (t >= NG) return;
    const float* gv = g + (size_t)t * REC;
    float gl[REC];
    #pragma unroll
    for (int k = 0; k < REC; ++k) gl[k] = gv[k];
    float acc = b2[0];
    for (int j = 0; j < OHID; ++j) {
        float s = b1[j];
        #pragma unroll
        for (int k = 0; k < REC; ++k) s += gl[k] * w1[k * OHID + j];
        acc += tanhf(s) * w2[j];
    }
    out[t] = acc;
}

extern "C" void kernel_launch(void* const* d_in, const int* in_sizes, int n_in,
                              void* d_out, int out_size, void* d_ws, size_t ws_size,
                              hipStream_t stream) {
    const float* atom    = (const float*)d_in[0];
    const float* bond    = (const float*)d_in[1];
    const int*   parent  = (const int*)d_in[2];
    const int*   child   = (const int*)d_in[3];
    const int*   depth   = (const int*)d_in[4];
    const int*   gid     = (const int*)d_in[5];
    const float* isr     = (const float*)d_in[6];
    const float* inner_w = (const float*)d_in[7];
    const float* inner_b = (const float*)d_in[8];
    const float* net_w1  = (const float*)d_in[9];
    const float* net_b1  = (const float*)d_in[10];
    const float* net_w2  = (const float*)d_in[11];
    const float* net_b2  = (const float*)d_in[12];
    const float* net0_w1 = (const float*)d_in[13];
    const float* net0_b1 = (const float*)d_in[14];
    const float* net0_w2 = (const float*)d_in[15];
    const float* net0_b2 = (const float*)d_in[16];
    const float* out_w1  = (const float*)d_in[17];
    const float* out_b1  = (const float*)d_in[18];
    const float* out_w2  = (const float*)d_in[19];
    const float* out_b2  = (const float*)d_in[20];
    float* out = (float*)d_out;

    char* ws = (char*)d_ws;
    size_t o = 0;
    float* msg_s    = (float*)(ws + o);  o += (size_t)NN * REC * 4;    // 83.9 MB
    int4* nodeinfo  = (int4*)(ws + o);   o += (size_t)NN * 16;         // 16.8 MB
    float* g        = (float*)(ws + o);  o += (size_t)NG * REC * 4;    // 1.3 MB
    int2* pnode2    = (int2*)(ws + o);   o += (size_t)NN * 8;          // 8.4 MB
    int* adjc       = (int*)(ws + o);    o += (size_t)NE * 4;          // 3.9 MB
    int* cnt_n      = (int*)(ws + o);    o += (size_t)NN * 4;          // 4.2 MB
    int* row_n      = (int*)(ws + o);    o += (size_t)NN * 4;          // 4.2 MB
    int* K_s        = (int*)(ws + o);    o += (size_t)NN * 4;          // 4.2 MB
    int* bin_cnt    = (int*)(ws + o);    o += (size_t)NBINS * 4;       // 128 KB
    int* bin_base   = (int*)(ws + o);    o += (size_t)NBINS * 4;       // 128 KB
    int* bin_cur    = (int*)(ws + o);    o += (size_t)NBINS * 4;       // 128 KB
    int* totals     = (int*)(ws + o);    o += 32 * 4;
    int* bars       = (int*)(ws + o);    o += 32 * 4;
    // total ~127 MB

    k_pre<<<1024, 256, 0, stream>>>(cnt_n, pnode2, g, bin_cnt, totals, bars);
    k_prep<<<NB, NT, 0, stream>>>(parent, child, depth, gid, isr,
                                  cnt_n, pnode2, K_s, nodeinfo, row_n,
                                  adjc, bin_cnt, bin_base, bin_cur, totals, bars);
    k_levels<<<NB2, NT2, 0, stream>>>(atom, bond, nodeinfo, adjc,
                                      bin_base, bin_cnt,
                                      inner_w, inner_b, net_w1, net_b1, net_w2, net_b2,
                                      net0_w1, net0_b1, net0_w2, net0_b2,
                                      g, msg_s);
    k_out<<<(NG + 255) / 256, 256, 0, stream>>>(g, out_w1, out_b1, out_w2, out_b2, out);
}

// Round 23
// 967.158 us; speedup vs baseline: 1.2111x; 1.2111x over previous
//
#include <hip/hip_runtime.h>

#define ATOM  14
#define BOND  3
#define INNER 20
#define HID   34
#define HIDP  36             // HID padded for LDS rows
#define REC   20
#define OHID  25
#define NN    1048576
#define NE    983040
#define NG    16384

#define NB    512            // prep persistent grid (contention-optimal, R22 A/B)
#define NT    256
#define GT    (NB*NT)        // 131072
#define NIT   (NN/GT)        // 8 strided iterations in node phases

#define NB2   1024           // level blocks (independent tree-bins)
#define NT2   256            // 4 waves
#define NGRP  (NT2/4)        // 64 node-groups (4 lanes each) per block
#define SSTR  (NGRP+1)       // 65: stride-padded staging
#define NBINS (NB2*32)       // bin = blk*32 + depth*2 + isLeaf

__device__ __forceinline__ float leaky(float x) { return x >= 0.f ? x : 0.01f * x; }

__device__ __forceinline__ void wsync() {
    __builtin_amdgcn_wave_barrier();
    __builtin_amdgcn_sched_barrier(0);
}

// grid-wide barrier for prep only: device-scope fences (cross-XCD safe)
__device__ __forceinline__ void gbar_f(int* bar, int goal) {
    __syncthreads();
    if (threadIdx.x == 0) {
        __threadfence();
        __hip_atomic_fetch_add(bar, 1, __ATOMIC_RELEASE, __HIP_MEMORY_SCOPE_AGENT);
        while (__hip_atomic_load(bar, __ATOMIC_RELAXED, __HIP_MEMORY_SCOPE_AGENT) < goal)
            __builtin_amdgcn_s_sleep(32);
        __threadfence();
    }
    __syncthreads();
}

__global__ void k_pre(int* cnt_n, int2* pnode2, float* g, int* bin_cnt, int* totals, int* bars) {
    int tid = blockIdx.x * 256 + threadIdx.x;          // 262144 threads
    for (int i = tid; i < NN; i += 262144) { cnt_n[i] = 0; pnode2[i] = make_int2(i, -1); }
    for (int i = tid; i < NG * REC; i += 262144) g[i] = 0.f;
    for (int i = tid; i < NBINS; i += 262144) bin_cnt[i] = 0;
    if (tid == 0) { totals[0] = 0; totals[16] = 0; }
    if (tid == 1) for (int k = 0; k < 32; ++k) bars[k] = 0;
}

// ---------------- prep: counts+rank, root-chase, sort, row-alloc, slot pass ----------------
__global__ __launch_bounds__(NT) void k_prep(
    const int* __restrict__ parent, const int* __restrict__ child,
    const int* __restrict__ depth, const int* __restrict__ gid,
    const float* __restrict__ isr,
    int* cnt_n, int2* pnode2, int* K_s, int* inv,
    int4* nodeinfo, int* row_pos, int* slot_c,
    int* bin_cnt, int* bin_base, int* bin_cur,
    int* totals, int* bar)
{
    __shared__ int sh[NT];
    __shared__ int sbase_sh;
    const int t = threadIdx.x;
    const int tid = blockIdx.x * NT + t;
    int ep = 0;

    // P0: child counts (returns rank) + packed (parent, rank|eid) per child
    for (int e = tid; e < NE; e += GT) {
        int p = parent[e];
        int r = atomicAdd(&cnt_n[p], 1);
        pnode2[child[e]] = make_int2(p, (r << 20) | e);
    }
    gbar_f(bar, NB * ++ep);

    // P1: per-node root chase + bin key + histogram
    for (int i = tid; i < NN; i += GT) {
        int d = depth[i];
        int r = i;
        for (int s = 0; s < d; ++s) r = pnode2[r].x;   // fixed-point safe at roots
        int K = (r & (NB2 - 1)) * 32 + d * 2 + (cnt_n[i] == 0 ? 1 : 0);
        K_s[i] = K;
        atomicAdd(&bin_cnt[K], 1);
    }
    gbar_f(bar, NB * ++ep);

    // P2: bin scan (orderless base): blocks 0..127, 256 bins each
    if (blockIdx.x < NBINS / NT) {
        int k0 = blockIdx.x * NT + t;
        int v = bin_cnt[k0];
        sh[t] = v;
        __syncthreads();
        for (int ofs = 1; ofs < NT; ofs <<= 1) {
            int x = (t >= ofs) ? sh[t - ofs] : 0;
            __syncthreads();
            sh[t] += x;
            __syncthreads();
        }
        if (t == NT - 1) sbase_sh = atomicAdd(&totals[0], sh[t]);
        __syncthreads();
        int b = sbase_sh + sh[t] - v;
        bin_base[k0] = b;
        bin_cur[k0] = b;
    }
    gbar_f(bar, NB * ++ep);

    // P3: counting-sort scatter (one 16B scattered write) + coalesced inv
    for (int i = tid; i < NN; i += GT) {
        int pos = atomicAdd(&bin_cur[K_s[i]], 1);
        int2 pe = pnode2[i];                 // coalesced
        int gr = (isr[i] != 0.f) ? gid[i] : -1;   // coalesced
        nodeinfo[pos] = make_int4(i, pe.y, gr, cnt_n[i]);  // scattered 16B
        inv[i] = pos;                        // coalesced
    }
    gbar_f(bar, NB * ++ep);

    // P4a: row allocation in POS order (level-compact rows); all coalesced
    for (int k = 0; k < NIT; ++k) {
        int pos = tid + k * GT;
        int cn = nodeinfo[pos].w;            // coalesced
        __syncthreads();                     // protect sh reuse
        sh[t] = cn;
        __syncthreads();
        for (int ofs = 1; ofs < NT; ofs <<= 1) {
            int x = (t >= ofs) ? sh[t - ofs] : 0;
            __syncthreads();
            sh[t] += x;
            __syncthreads();
        }
        if (t == NT - 1) sbase_sh = atomicAdd(&totals[16], sh[t]);
        __syncthreads();
        row_pos[pos] = sbase_sh + sh[t] - cn;   // coalesced
    }
    gbar_f(bar, NB * ++ep);

    // P4b: slot pass in pos order — NO scattered writes (slot_c coalesced)
    for (int pos = tid; pos < NN; pos += GT) {
        int4 ni = nodeinfo[pos];             // coalesced
        if (ni.z < 0) {                      // non-root => has a parent edge
            int ppn  = pnode2[ni.x].x;       // scattered read (hot 8MB)
            int ppos = inv[ppn];             // scattered read (4MB)
            int rank = ((unsigned)ni.y) >> 20;
            slot_c[pos] = row_pos[ppos] + rank;  // scattered read + coalesced write
        }
    }
}

// cooperative MLP phases 1-2 (x pre-staged in xs column `slot`): lane j owns
// hidden units 9j..9j+8 and outputs 5j..5j+4. Result: o[5] + os column.
__device__ __forceinline__ void coop_mlp(int slot, int j, int KN,
                                         const float* xs, float* hs, float* os,
                                         const float* w1, const float* b1,
                                         const float* w2, const float* b2,
                                         float* o)
{
    wsync();                       // xs writes (all lanes) before xs reads
    float acc[9];
    #pragma unroll
    for (int u = 0; u < 9; ++u) { int h = 9*j + u; acc[u] = (h < HID) ? b1[h] : 0.f; }
    #pragma unroll 2
    for (int k = 0; k < KN; ++k) {
        float xk = xs[k * SSTR + slot];
        #pragma unroll
        for (int u = 0; u < 9; ++u) { int h = 9*j + u; if (h < HID) acc[u] += xk * w1[k * HIDP + h]; }
    }
    #pragma unroll
    for (int u = 0; u < 9; ++u) { int h = 9*j + u; if (h < HID) hs[h * SSTR + slot] = leaky(acc[u]); }
    wsync();                       // hs writes before hs reads
    #pragma unroll
    for (int u = 0; u < 5; ++u) o[u] = b2[5*j + u];
    #pragma unroll 2
    for (int k = 0; k < HID; ++k) {
        float hk = hs[k * SSTR + slot];
        #pragma unroll
        for (int u = 0; u < 5; ++u) o[u] += hk * w2[k * REC + 5*j + u];
    }
    #pragma unroll
    for (int u = 0; u < 5; ++u) { o[u] = leaky(o[u]); os[(5*j + u) * SSTR + slot] = o[u]; }
    wsync();                       // os writes before os reads (msg phase)
}

// ---------------- levels: row-major msgs — contiguous gathers, no adjc ----------------
__global__ __launch_bounds__(NT2) void k_levels(
    const float* __restrict__ atom, const float* __restrict__ bond,
    const int4* __restrict__ nodeinfo, const int* __restrict__ row_pos,
    const int* __restrict__ slot_c,
    const int* __restrict__ bin_base, const int* __restrict__ bin_cnt,
    const float* __restrict__ iw, const float* __restrict__ ib,
    const float* __restrict__ nw1, const float* __restrict__ nb1,
    const float* __restrict__ nw2, const float* __restrict__ nb2,
    const float* __restrict__ l0w1, const float* __restrict__ l0b1,
    const float* __restrict__ l0w2, const float* __restrict__ l0b2,
    float* __restrict__ g, float* __restrict__ msg_row)
{
    __shared__ float lw1[34 * HIDP];     // net_w1  [34][36]
    __shared__ float lw2[HID * REC];     // net_w2  [34][20]
    __shared__ float liw[23 * REC];      // inner_w [23][20]
    __shared__ float zw1[ATOM * HIDP];   // net0_w1 [14][36]
    __shared__ float zw2[HID * REC];     // net0_w2 [34][20]
    __shared__ float lb1[HID], lb2[REC], lbi[INNER], zb1[HID], zb2[REC];
    __shared__ float xs[34 * SSTR];      // x staging   [34][65]
    __shared__ float hs[34 * SSTR];      // hid staging [34][65]
    __shared__ float os[20 * SSTR];      // out staging [20][65]

    const int t = threadIdx.x;
    const int b = blockIdx.x;
    const int slot = t >> 2;             // node-group 0..63
    const int j = t & 3;                 // lane slice 0..3

    for (int idx = t; idx < 34 * HIDP; idx += NT2) {
        int r = idx / HIDP, c = idx - r * HIDP;
        lw1[idx] = (c < HID) ? nw1[r * HID + c] : 0.f;
    }
    for (int idx = t; idx < HID * REC; idx += NT2) { lw2[idx] = nw2[idx]; zw2[idx] = l0w2[idx]; }
    for (int idx = t; idx < 23 * REC; idx += NT2) liw[idx] = iw[idx];
    for (int idx = t; idx < ATOM * HIDP; idx += NT2) {
        int r = idx / HIDP, c = idx - r * HIDP;
        zw1[idx] = (c < HID) ? l0w1[r * HID + c] : 0.f;
    }
    if (t < HID) { lb1[t] = nb1[t]; zb1[t] = l0b1[t]; }
    else if (t >= 64 && t < 64 + REC) { lb2[t - 64] = nb2[t - 64]; zb2[t - 64] = l0b2[t - 64]; }
    if (t >= 96 && t < 96 + INNER) lbi[t - 96] = ib[t - 96];
    __syncthreads();

    for (int d = 15; d >= 0; --d) {
        // ---- internal nodes (bin b*32 + d*2) ----
        {
            int K = b * 32 + d * 2;
            int base = bin_base[K], n0 = bin_cnt[K];
            for (int idx = slot; idx < n0; idx += NGRP) {
                int pos = base + idx;
                int4 ni = nodeinfo[pos];                // {i, rank|eid, gr, n}
                int n   = ni.w;
                int row = row_pos[pos];
                // gather: children rows contiguous; lane j sums slice [5j,5j+5)
                float s0 = 0.f, s1 = 0.f, s2 = 0.f, s3 = 0.f, s4 = 0.f;
                const float* mp = msg_row + (size_t)row * REC + 5*j;
                for (int r = 0; r < n; ++r, mp += REC) {
                    s0 += mp[0]; s1 += mp[1]; s2 += mp[2]; s3 += mp[3]; s4 += mp[4];
                }
                // stage x = [atom, isum]
                const float* ar = atom + (size_t)ni.x * ATOM;
                #pragma unroll
                for (int u = 0; u < 4; ++u) { int k = 4*j + u; if (k < ATOM) xs[k * SSTR + slot] = ar[k]; }
                xs[(ATOM + 5*j + 0) * SSTR + slot] = s0;
                xs[(ATOM + 5*j + 1) * SSTR + slot] = s1;
                xs[(ATOM + 5*j + 2) * SSTR + slot] = s2;
                xs[(ATOM + 5*j + 3) * SSTR + slot] = s3;
                xs[(ATOM + 5*j + 4) * SSTR + slot] = s4;
                float o[5];
                coop_mlp(slot, j, ATOM + INNER, xs, hs, os, lw1, lb1, lw2, lb2, o);
                if (ni.z >= 0) {
                    #pragma unroll
                    for (int u = 0; u < 5; ++u) atomicAdd(&g[(size_t)ni.z * REC + 5*j + u], o[u]);
                } else {
                    const float* br = bond + (size_t)(ni.y & 0xFFFFF) * BOND;
                    float b0 = br[0], b1 = br[1], b2 = br[2];
                    float m[5];
                    #pragma unroll
                    for (int u = 0; u < 5; ++u)
                        m[u] = lbi[5*j + u] + b0 * liw[0 * INNER + 5*j + u]
                             + b1 * liw[1 * INNER + 5*j + u] + b2 * liw[2 * INNER + 5*j + u];
                    #pragma unroll 2
                    for (int k = 0; k < REC; ++k) {
                        float ok = os[k * SSTR + slot];
                        #pragma unroll
                        for (int u = 0; u < 5; ++u) m[u] += ok * liw[(BOND + k) * INNER + 5*j + u];
                    }
                    float* mw = msg_row + (size_t)slot_c[pos] * REC + 5*j;
                    #pragma unroll
                    for (int u = 0; u < 5; ++u) mw[u] = leaky(m[u]);
                }
            }
        }
        // ---- leaves (bin b*32 + d*2 + 1) ----
        {
            int K = b * 32 + d * 2 + 1;
            int base = bin_base[K], n1 = bin_cnt[K];
            for (int idx = slot; idx < n1; idx += NGRP) {
                int pos = base + idx;
                int4 ni = nodeinfo[pos];
                const float* ar = atom + (size_t)ni.x * ATOM;
                #pragma unroll
                for (int u = 0; u < 4; ++u) { int k = 4*j + u; if (k < ATOM) xs[k * SSTR + slot] = ar[k]; }
                float o[5];
                coop_mlp(slot, j, ATOM, xs, hs, os, zw1, zb1, zw2, zb2, o);
                if (ni.z >= 0) {
                    #pragma unroll
                    for (int u = 0; u < 5; ++u) atomicAdd(&g[(size_t)ni.z * REC + 5*j + u], o[u]);
                } else {
                    const float* br = bond + (size_t)(ni.y & 0xFFFFF) * BOND;
                    float b0 = br[0], b1 = br[1], b2 = br[2];
                    float m[5];
                    #pragma unroll
                    for (int u = 0; u < 5; ++u)
                        m[u] = lbi[5*j + u] + b0 * liw[0 * INNER + 5*j + u]
                             + b1 * liw[1 * INNER + 5*j + u] + b2 * liw[2 * INNER + 5*j + u];
                    #pragma unroll 2
                    for (int k = 0; k < REC; ++k) {
                        float ok = os[k * SSTR + slot];
                        #pragma unroll
                        for (int u = 0; u < 5; ++u) m[u] += ok * liw[(BOND + k) * INNER + 5*j + u];
                    }
                    float* mw = msg_row + (size_t)slot_c[pos] * REC + 5*j;
                    #pragma unroll
                    for (int u = 0; u < 5; ++u) mw[u] = leaky(m[u]);
                }
            }
        }
        // block-local level barrier (msg producer->consumer across waves)
        __threadfence_block();
        __syncthreads();
    }
}

// ---------------- readout ----------------
__global__ void k_out(const float* __restrict__ g,
                      const float* __restrict__ w1, const float* __restrict__ b1,
                      const float* __restrict__ w2, const float* __restrict__ b2,
                      float* __restrict__ out) {
    int t = blockIdx.x * 256 + threadIdx.x;
    if (t >= NG) return;
    const float* gv = g + (size_t)t * REC;
    float gl[REC];
    #pragma unroll
    for (int k = 0; k < REC; ++k) gl[k] = gv[k];
    float acc = b2[0];
    for (int j = 0; j < OHID; ++j) {
        float s = b1[j];
        #pragma unroll
        for (int k = 0; k < REC; ++k) s += gl[k] * w1[k * OHID + j];
        acc += tanhf(s) * w2[j];
    }
    out[t] = acc;
}

extern "C" void kernel_launch(void* const* d_in, const int* in_sizes, int n_in,
                              void* d_out, int out_size, void* d_ws, size_t ws_size,
                              hipStream_t stream) {
    const float* atom    = (const float*)d_in[0];
    const float* bond    = (const float*)d_in[1];
    const int*   parent  = (const int*)d_in[2];
    const int*   child   = (const int*)d_in[3];
    const int*   depth   = (const int*)d_in[4];
    const int*   gid     = (const int*)d_in[5];
    const float* isr     = (const float*)d_in[6];
    const float* inner_w = (const float*)d_in[7];
    const float* inner_b = (const float*)d_in[8];
    const float* net_w1  = (const float*)d_in[9];
    const float* net_b1  = (const float*)d_in[10];
    const float* net_w2  = (const float*)d_in[11];
    const float* net_b2  = (const float*)d_in[12];
    const float* net0_w1 = (const float*)d_in[13];
    const float* net0_b1 = (const float*)d_in[14];
    const float* net0_w2 = (const float*)d_in[15];
    const float* net0_b2 = (const float*)d_in[16];
    const float* out_w1  = (const float*)d_in[17];
    const float* out_b1  = (const float*)d_in[18];
    const float* out_w2  = (const float*)d_in[19];
    const float* out_b2  = (const float*)d_in[20];
    float* out = (float*)d_out;

    char* ws = (char*)d_ws;
    size_t o = 0;
    float* msg_row  = (float*)(ws + o);  o += (size_t)NE * REC * 4;    // 78.6 MB
    int4* nodeinfo  = (int4*)(ws + o);   o += (size_t)NN * 16;         // 16.8 MB
    float* g        = (float*)(ws + o);  o += (size_t)NG * REC * 4;    // 1.3 MB
    int2* pnode2    = (int2*)(ws + o);   o += (size_t)NN * 8;          // 8.4 MB
    int* cnt_n      = (int*)(ws + o);    o += (size_t)NN * 4;          // 4.2 MB
    int* inv        = (int*)(ws + o);    o += (size_t)NN * 4;          // 4.2 MB
    int* row_pos    = (int*)(ws + o);    o += (size_t)NN * 4;          // 4.2 MB
    int* slot_c     = (int*)(ws + o);    o += (size_t)NN * 4;          // 4.2 MB
    int* K_s        = (int*)(ws + o);    o += (size_t)NN * 4;          // 4.2 MB
    int* bin_cnt    = (int*)(ws + o);    o += (size_t)NBINS * 4;       // 128 KB
    int* bin_base   = (int*)(ws + o);    o += (size_t)NBINS * 4;       // 128 KB
    int* bin_cur    = (int*)(ws + o);    o += (size_t)NBINS * 4;       // 128 KB
    int* totals     = (int*)(ws + o);    o += 32 * 4;
    int* bars       = (int*)(ws + o);    o += 32 * 4;
    // total ~127 MB

    k_pre<<<1024, 256, 0, stream>>>(cnt_n, pnode2, g, bin_cnt, totals, bars);
    k_prep<<<NB, NT, 0, stream>>>(parent, child, depth, gid, isr,
                                  cnt_n, pnode2, K_s, inv, nodeinfo, row_pos,
                                  slot_c, bin_cnt, bin_base, bin_cur, totals, bars);
    k_levels<<<NB2, NT2, 0, stream>>>(atom, bond, nodeinfo, row_pos, slot_c,
                                      bin_base, bin_cnt,
                                      inner_w, inner_b, net_w1, net_b1, net_w2, net_b2,
                                      net0_w1, net0_b1, net0_w2, net0_b2,
                                      g, msg_row);
    k_out<<<(NG + 255) / 256, 256, 0, stream>>>(g, out_w1, out_b1, out_w2, out_b2, out);
}

// Round 24
// 900.522 us; speedup vs baseline: 1.3007x; 1.0740x over previous
//
#include <hip/hip_runtime.h>

#define ATOM  14
#define BOND  3
#define INNER 20
#define HID   34
#define HIDP  36             // HID padded for LDS rows
#define REC   20
#define OHID  25
#define NN    1048576
#define NE    983040
#define NG    16384

#define NB    512            // prep persistent grid (contention-optimal: 512 > 1024, R22 A/B)
#define NT    256
#define GT    (NB*NT)        // 131072
#define NIT   (NN/GT)        // 8 strided iterations in node phases

#define NB2   1024           // level blocks (independent tree-bins)
#define NT2   256            // 4 waves
#define NGRP  (NT2/4)        // 64 node-groups (4 lanes each) per block
#define SSTR  (NGRP+1)       // 65: stride-padded staging
#define NBINS (NB2*32)       // bin = blk*32 + depth*2 + isLeaf

__device__ __forceinline__ float leaky(float x) { return x >= 0.f ? x : 0.01f * x; }

__device__ __forceinline__ void wsync() {
    __builtin_amdgcn_wave_barrier();
    __builtin_amdgcn_sched_barrier(0);
}

// grid-wide barrier for prep only: device-scope fences (cross-XCD safe)
__device__ __forceinline__ void gbar_f(int* bar, int goal) {
    __syncthreads();
    if (threadIdx.x == 0) {
        __threadfence();
        __hip_atomic_fetch_add(bar, 1, __ATOMIC_RELEASE, __HIP_MEMORY_SCOPE_AGENT);
        while (__hip_atomic_load(bar, __ATOMIC_RELAXED, __HIP_MEMORY_SCOPE_AGENT) < goal)
            __builtin_amdgcn_s_sleep(32);
        __threadfence();
    }
    __syncthreads();
}

__global__ void k_pre(int* cnt_n, int2* pnode2, float* g, int* bin_cnt, int* totals, int* bars) {
    int tid = blockIdx.x * 256 + threadIdx.x;          // 262144 threads
    for (int i = tid; i < NN; i += 262144) { cnt_n[i] = 0; pnode2[i] = make_int2(i, -1); }
    for (int i = tid; i < NG * REC; i += 262144) g[i] = 0.f;
    for (int i = tid; i < NBINS; i += 262144) bin_cnt[i] = 0;
    if (tid == 0) { totals[0] = 0; totals[16] = 0; }
    if (tid == 1) for (int k = 0; k < 32; ++k) bars[k] = 0;
}

// ---------------- prep: counts+rank, root-chase, sort+row-alloc, child pass ----------------
__global__ __launch_bounds__(NT) void k_prep(
    const int* __restrict__ parent, const int* __restrict__ child,
    const int* __restrict__ depth, const int* __restrict__ gid,
    const float* __restrict__ isr,
    int* cnt_n, int2* pnode2, int* K_s,
    int4* nodeinfo, int* row_n, int* adjc,
    int* bin_cnt, int* bin_base, int* bin_cur,
    int* totals, int* bar)
{
    __shared__ int sh[NT];
    __shared__ int sbase_sh;
    const int t = threadIdx.x;
    const int tid = blockIdx.x * NT + t;
    int ep = 0;

    // P0: child counts (returns rank) + packed (parent, rank|eid) per child
    for (int e = tid; e < NE; e += GT) {
        int p = parent[e];
        int r = atomicAdd(&cnt_n[p], 1);
        pnode2[child[e]] = make_int2(p, (r << 20) | e);
    }
    gbar_f(bar, NB * ++ep);

    // P1: per-node root chase + bin key + histogram
    for (int i = tid; i < NN; i += GT) {
        int d = depth[i];
        int r = i;
        for (int s = 0; s < d; ++s) r = pnode2[r].x;   // fixed-point safe at roots
        int K = (r & (NB2 - 1)) * 32 + d * 2 + (cnt_n[i] == 0 ? 1 : 0);
        K_s[i] = K;
        atomicAdd(&bin_cnt[K], 1);
    }
    gbar_f(bar, NB * ++ep);

    // P2: bin scan (orderless base): blocks 0..127, 256 bins each
    if (blockIdx.x < NBINS / NT) {
        int k0 = blockIdx.x * NT + t;
        int v = bin_cnt[k0];
        sh[t] = v;
        __syncthreads();
        for (int ofs = 1; ofs < NT; ofs <<= 1) {
            int x = (t >= ofs) ? sh[t - ofs] : 0;
            __syncthreads();
            sh[t] += x;
            __syncthreads();
        }
        if (t == NT - 1) sbase_sh = atomicAdd(&totals[0], sh[t]);
        __syncthreads();
        int b = sbase_sh + sh[t] - v;
        bin_base[k0] = b;
        bin_cur[k0] = b;
    }
    gbar_f(bar, NB * ++ep);

    // P3: counting-sort scatter + fused orderless row allocation.
    // One packed 16B scattered write per node; row_n coalesced.
    for (int k = 0; k < NIT; ++k) {
        int i = tid + k * GT;
        int cn = cnt_n[i];
        __syncthreads();                     // protect sh reuse
        sh[t] = cn;
        __syncthreads();
        for (int ofs = 1; ofs < NT; ofs <<= 1) {
            int x = (t >= ofs) ? sh[t - ofs] : 0;
            __syncthreads();
            sh[t] += x;
            __syncthreads();
        }
        if (t == NT - 1) sbase_sh = atomicAdd(&totals[16], sh[t]);
        __syncthreads();
        int row = sbase_sh + sh[t] - cn;     // exclusive prefix + block base
        int pos = atomicAdd(&bin_cur[K_s[i]], 1);
        int2 pe = pnode2[i];                 // coalesced
        int gr = (isr[i] != 0.f) ? gid[i] : -1;   // coalesced
        nodeinfo[pos] = make_int4(i, pe.y, gr, (row << 12) | cn);  // scattered 16B
        row_n[i] = row;                      // coalesced
    }
    gbar_f(bar, NB * ++ep);

    // P4: child pass in pos order — no atomics; only adjc is a scattered write
    for (int pos = tid; pos < NN; pos += GT) {
        int4 ni = nodeinfo[pos];             // coalesced
        if (ni.z < 0) {                      // non-root => has a parent edge
            int ppn = pnode2[ni.x].x;        // scattered read (hot 8MB)
            int rank = ((unsigned)ni.y) >> 20;
            int slot = row_n[ppn] + rank;    // scattered read (4MB)
            adjc[slot] = pos;                // scattered 4B write
        }
    }
}

// cooperative MLP phases 1-2 (x pre-staged in xs column `slot`): lane j owns
// hidden units 9j..9j+8 and outputs 5j..5j+4. Result: o[5] + os column.
__device__ __forceinline__ void coop_mlp(int slot, int j, int KN,
                                         const float* xs, float* hs, float* os,
                                         const float* w1, const float* b1,
                                         const float* w2, const float* b2,
                                         float* o)
{
    wsync();                       // xs writes (all lanes) before xs reads
    float acc[9];
    #pragma unroll
    for (int u = 0; u < 9; ++u) { int h = 9*j + u; acc[u] = (h < HID) ? b1[h] : 0.f; }
    #pragma unroll 2
    for (int k = 0; k < KN; ++k) {
        float xk = xs[k * SSTR + slot];
        #pragma unroll
        for (int u = 0; u < 9; ++u) { int h = 9*j + u; if (h < HID) acc[u] += xk * w1[k * HIDP + h]; }
    }
    #pragma unroll
    for (int u = 0; u < 9; ++u) { int h = 9*j + u; if (h < HID) hs[h * SSTR + slot] = leaky(acc[u]); }
    wsync();                       // hs writes before hs reads
    #pragma unroll
    for (int u = 0; u < 5; ++u) o[u] = b2[5*j + u];
    #pragma unroll 2
    for (int k = 0; k < HID; ++k) {
        float hk = hs[k * SSTR + slot];
        #pragma unroll
        for (int u = 0; u < 5; ++u) o[u] += hk * w2[k * REC + 5*j + u];
    }
    #pragma unroll
    for (int u = 0; u < 5; ++u) { o[u] = leaky(o[u]); os[(5*j + u) * SSTR + slot] = o[u]; }
    wsync();                       // os writes before os reads (msg phase)
}

// ---------------- levels: 4 lanes per node, packed nodeinfo, bond by eid ----------------
__global__ __launch_bounds__(NT2) void k_levels(
    const float* __restrict__ atom, const float* __restrict__ bond,
    const int4* __restrict__ nodeinfo, const int* __restrict__ adjc,
    const int* __restrict__ bin_base, const int* __restrict__ bin_cnt,
    const float* __restrict__ iw, const float* __restrict__ ib,
    const float* __restrict__ nw1, const float* __restrict__ nb1,
    const float* __restrict__ nw2, const float* __restrict__ nb2,
    const float* __restrict__ l0w1, const float* __restrict__ l0b1,
    const float* __restrict__ l0w2, const float* __restrict__ l0b2,
    float* __restrict__ g, float* __restrict__ msg_s)
{
    __shared__ float lw1[34 * HIDP];     // net_w1  [34][36]
    __shared__ float lw2[HID * REC];     // net_w2  [34][20]
    __shared__ float liw[23 * REC];      // inner_w [23][20]
    __shared__ float zw1[ATOM * HIDP];   // net0_w1 [14][36]
    __shared__ float zw2[HID * REC];     // net0_w2 [34][20]
    __shared__ float lb1[HID], lb2[REC], lbi[INNER], zb1[HID], zb2[REC];
    __shared__ float xs[34 * SSTR];      // x staging   [34][65]
    __shared__ float hs[34 * SSTR];      // hid staging [34][65]
    __shared__ float os[20 * SSTR];      // out staging [20][65]

    const int t = threadIdx.x;
    const int b = blockIdx.x;
    const int slot = t >> 2;             // node-group 0..63
    const int j = t & 3;                 // lane slice 0..3

    for (int idx = t; idx < 34 * HIDP; idx += NT2) {
        int r = idx / HIDP, c = idx - r * HIDP;
        lw1[idx] = (c < HID) ? nw1[r * HID + c] : 0.f;
    }
    for (int idx = t; idx < HID * REC; idx += NT2) { lw2[idx] = nw2[idx]; zw2[idx] = l0w2[idx]; }
    for (int idx = t; idx < 23 * REC; idx += NT2) liw[idx] = iw[idx];
    for (int idx = t; idx < ATOM * HIDP; idx += NT2) {
        int r = idx / HIDP, c = idx - r * HIDP;
        zw1[idx] = (c < HID) ? l0w1[r * HID + c] : 0.f;
    }
    if (t < HID) { lb1[t] = nb1[t]; zb1[t] = l0b1[t]; }
    else if (t >= 64 && t < 64 + REC) { lb2[t - 64] = nb2[t - 64]; zb2[t - 64] = l0b2[t - 64]; }
    if (t >= 96 && t < 96 + INNER) lbi[t - 96] = ib[t - 96];
    __syncthreads();

    for (int d = 15; d >= 0; --d) {
        // ---- internal nodes (bin b*32 + d*2) ----
        {
            int K = b * 32 + d * 2;
            int base = bin_base[K], n0 = bin_cnt[K];
            for (int idx = slot; idx < n0; idx += NGRP) {
                int pos = base + idx;
                int4 ni = nodeinfo[pos];                // {i, rank|eid, gr, row|n}
                int n   = ni.w & 0xFFF;
                int rp0 = ((unsigned)ni.w) >> 12;
                // gather: lane j sums msg slice q in [5j,5j+5)
                float s0 = 0.f, s1 = 0.f, s2 = 0.f, s3 = 0.f, s4 = 0.f;
                for (int r = rp0; r < rp0 + n; ++r) {
                    const float* mp = msg_s + (size_t)adjc[r] * REC + 5*j;
                    s0 += mp[0]; s1 += mp[1]; s2 += mp[2]; s3 += mp[3]; s4 += mp[4];
                }
                // stage x = [atom, isum]
                const float* ar = atom + (size_t)ni.x * ATOM;
                #pragma unroll
                for (int u = 0; u < 4; ++u) { int k = 4*j + u; if (k < ATOM) xs[k * SSTR + slot] = ar[k]; }
                xs[(ATOM + 5*j + 0) * SSTR + slot] = s0;
                xs[(ATOM + 5*j + 1) * SSTR + slot] = s1;
                xs[(ATOM + 5*j + 2) * SSTR + slot] = s2;
                xs[(ATOM + 5*j + 3) * SSTR + slot] = s3;
                xs[(ATOM + 5*j + 4) * SSTR + slot] = s4;
                float o[5];
                coop_mlp(slot, j, ATOM + INNER, xs, hs, os, lw1, lb1, lw2, lb2, o);
                if (ni.z >= 0) {
                    #pragma unroll
                    for (int u = 0; u < 5; ++u) atomicAdd(&g[(size_t)ni.z * REC + 5*j + u], o[u]);
                } else {
                    const float* br = bond + (size_t)(ni.y & 0xFFFFF) * BOND;
                    float b0 = br[0], b1 = br[1], b2 = br[2];
                    float m[5];
                    #pragma unroll
                    for (int u = 0; u < 5; ++u)
                        m[u] = lbi[5*j + u] + b0 * liw[0 * INNER + 5*j + u]
                             + b1 * liw[1 * INNER + 5*j + u] + b2 * liw[2 * INNER + 5*j + u];
                    #pragma unroll 2
                    for (int k = 0; k < REC; ++k) {
                        float ok = os[k * SSTR + slot];
                        #pragma unroll
                        for (int u = 0; u < 5; ++u) m[u] += ok * liw[(BOND + k) * INNER + 5*j + u];
                    }
                    #pragma unroll
                    for (int u = 0; u < 5; ++u) msg_s[(size_t)pos * REC + 5*j + u] = leaky(m[u]);
                }
            }
        }
        // ---- leaves (bin b*32 + d*2 + 1) ----
        {
            int K = b * 32 + d * 2 + 1;
            int base = bin_base[K], n1 = bin_cnt[K];
            for (int idx = slot; idx < n1; idx += NGRP) {
                int pos = base + idx;
                int4 ni = nodeinfo[pos];
                const float* ar = atom + (size_t)ni.x * ATOM;
                #pragma unroll
                for (int u = 0; u < 4; ++u) { int k = 4*j + u; if (k < ATOM) xs[k * SSTR + slot] = ar[k]; }
                float o[5];
                coop_mlp(slot, j, ATOM, xs, hs, os, zw1, zb1, zw2, zb2, o);
                if (ni.z >= 0) {
                    #pragma unroll
                    for (int u = 0; u < 5; ++u) atomicAdd(&g[(size_t)ni.z * REC + 5*j + u], o[u]);
                } else {
                    const float* br = bond + (size_t)(ni.y & 0xFFFFF) * BOND;
                    float b0 = br[0], b1 = br[1], b2 = br[2];
                    float m[5];
                    #pragma unroll
                    for (int u = 0; u < 5; ++u)
                        m[u] = lbi[5*j + u] + b0 * liw[0 * INNER + 5*j + u]
                             + b1 * liw[1 * INNER + 5*j + u] + b2 * liw[2 * INNER + 5*j + u];
                    #pragma unroll 2
                    for (int k = 0; k < REC; ++k) {
                        float ok = os[k * SSTR + slot];
                        #pragma unroll
                        for (int u = 0; u < 5; ++u) m[u] += ok * liw[(BOND + k) * INNER + 5*j + u];
                    }
                    #pragma unroll
                    for (int u = 0; u < 5; ++u) msg_s[(size_t)pos * REC + 5*j + u] = leaky(m[u]);
                }
            }
        }
        // block-local level barrier (msg producer->consumer across waves)
        __threadfence_block();
        __syncthreads();
    }
}

// ---------------- readout ----------------
__global__ void k_out(const float* __restrict__ g,
                      const float* __restrict__ w1, const float* __restrict__ b1,
                      const float* __restrict__ w2, const float* __restrict__ b2,
                      float* __restrict__ out) {
    int t = blockIdx.x * 256 + threadIdx.x;
    if (t >= NG) return;
    const float* gv = g + (size_t)t * REC;
    float gl[REC];
    #pragma unroll
    for (int k = 0; k < REC; ++k) gl[k] = gv[k];
    float acc = b2[0];
    for (int j = 0; j < OHID; ++j) {
        float s = b1[j];
        #pragma unroll
        for (int k = 0; k < REC; ++k) s += gl[k] * w1[k * OHID + j];
        acc += tanhf(s) * w2[j];
    }
    out[t] = acc;
}

extern "C" void kernel_launch(void* const* d_in, const int* in_sizes, int n_in,
                              void* d_out, int out_size, void* d_ws, size_t ws_size,
                              hipStream_t stream) {
    const float* atom    = (const float*)d_in[0];
    const float* bond    = (const float*)d_in[1];
    const int*   parent  = (const int*)d_in[2];
    const int*   child   = (const int*)d_in[3];
    const int*   depth   = (const int*)d_in[4];
    const int*   gid     = (const int*)d_in[5];
    const float* isr     = (const float*)d_in[6];
    const float* inner_w = (const float*)d_in[7];
    const float* inner_b = (const float*)d_in[8];
    const float* net_w1  = (const float*)d_in[9];
    const float* net_b1  = (const float*)d_in[10];
    const float* net_w2  = (const float*)d_in[11];
    const float* net_b2  = (const float*)d_in[12];
    const float* net0_w1 = (const float*)d_in[13];
    const float* net0_b1 = (const float*)d_in[14];
    const float* net0_w2 = (const float*)d_in[15];
    const float* net0_b2 = (const float*)d_in[16];
    const float* out_w1  = (const float*)d_in[17];
    const float* out_b1  = (const float*)d_in[18];
    const float* out_w2  = (const float*)d_in[19];
    const float* out_b2  = (const float*)d_in[20];
    float* out = (float*)d_out;

    char* ws = (char*)d_ws;
    size_t o = 0;
    float* msg_s    = (float*)(ws + o);  o += (size_t)NN * REC * 4;    // 83.9 MB
    int4* nodeinfo  = (int4*)(ws + o);   o += (size_t)NN * 16;         // 16.8 MB
    float* g        = (float*)(ws + o);  o += (size_t)NG * REC * 4;    // 1.3 MB
    int2* pnode2    = (int2*)(ws + o);   o += (size_t)NN * 8;          // 8.4 MB
    int* adjc       = (int*)(ws + o);    o += (size_t)NE * 4;          // 3.9 MB
    int* cnt_n      = (int*)(ws + o);    o += (size_t)NN * 4;          // 4.2 MB
    int* row_n      = (int*)(ws + o);    o += (size_t)NN * 4;          // 4.2 MB
    int* K_s        = (int*)(ws + o);    o += (size_t)NN * 4;          // 4.2 MB
    int* bin_cnt    = (int*)(ws + o);    o += (size_t)NBINS * 4;       // 128 KB
    int* bin_base   = (int*)(ws + o);    o += (size_t)NBINS * 4;       // 128 KB
    int* bin_cur    = (int*)(ws + o);    o += (size_t)NBINS * 4;       // 128 KB
    int* totals     = (int*)(ws + o);    o += 32 * 4;
    int* bars       = (int*)(ws + o);    o += 32 * 4;
    // total ~127 MB

    k_pre<<<1024, 256, 0, stream>>>(cnt_n, pnode2, g, bin_cnt, totals, bars);
    k_prep<<<NB, NT, 0, stream>>>(parent, child, depth, gid, isr,
                                  cnt_n, pnode2, K_s, nodeinfo, row_n,
                                  adjc, bin_cnt, bin_base, bin_cur, totals, bars);
    k_levels<<<NB2, NT2, 0, stream>>>(atom, bond, nodeinfo, adjc,
                                      bin_base, bin_cnt,
                                      inner_w, inner_b, net_w1, net_b1, net_w2, net_b2,
                                      net0_w1, net0_b1, net0_w2, net0_b2,
                                      g, msg_s);
    k_out<<<(NG + 255) / 256, 256, 0, stream>>>(g, out_w1, out_b1, out_w2, out_b2, out);
}